// Round 1
// 302.548 us; speedup vs baseline: 1.0051x; 1.0051x over previous
//
#include <hip/hip_runtime.h>
#include <hip/hip_bf16.h>
#include <stdint.h>

#define N_NODES 100000
#define DEG 16
#define D_IN 128
#define D_OUT 256
#define K_TOP 32
#define K_CAT 256   // concatenated K = D_IN(self) + D_IN(neigh)

typedef __attribute__((ext_vector_type(8))) short short8;
typedef __attribute__((ext_vector_type(4))) float floatx4;

__device__ __forceinline__ unsigned pack_bf16_rne(float f) {
    union { float f; unsigned u; } c; c.f = f;
    unsigned u = c.u;
    return (u + 0x7fffu + ((u >> 16) & 1u)) >> 16;   // round-to-nearest-even
}
__device__ __forceinline__ float bf16lo_to_f(unsigned lo16) {
    union { unsigned u; float f; } c; c.u = lo16 << 16; return c.f;
}

// async global->LDS, 16B per lane; LDS dest is wave-uniform base + lane*16
typedef __attribute__((address_space(1))) void as1_void;
typedef __attribute__((address_space(3))) void as3_void;
__device__ __forceinline__ void gload_lds16(const void* g, void* l) {
    __builtin_amdgcn_global_load_lds((as1_void*)g, (as3_void*)l, 16, 0, 0);
}

// ---------------- kernel 1: pack [w_self | w_neigh] -> bf16 B[256][256] ----------------
__global__ __launch_bounds__(256) void k_packw(const float* __restrict__ w_self,
                                               const float* __restrict__ w_neigh,
                                               unsigned short* __restrict__ bmat) {
    int o = blockIdx.x;      // 0..255 output channel
    int k = threadIdx.x;     // 0..255 concat-K
    float v = (k < D_IN) ? w_self[o * D_IN + k] : w_neigh[o * D_IN + (k - D_IN)];
    bmat[o * K_CAT + k] = (unsigned short)pack_bf16_rne(v);
}

// ------------- kernel 2: densify via LDS ds_add_f32 scatter + feat->bf16 ---------------
#define DROWS 64
__global__ __launch_bounds__(256) void k_densify(const float* __restrict__ topk_v,
                                                 const int* __restrict__ topk_i,
                                                 const float* __restrict__ feat,
                                                 unsigned short* __restrict__ xbf,
                                                 unsigned short* __restrict__ abf) {
    __shared__ float sx[DROWS * D_IN];   // 32 KiB
    const int t = threadIdx.x;
    const int row0 = blockIdx.x * DROWS;

    // zero LDS: 8192 floats / 256 thr = 8 float4 per thread
    #pragma unroll
    for (int p = 0; p < 8; ++p)
        *(floatx4*)&sx[(t + p * 256) * 4] = (floatx4){0.f, 0.f, 0.f, 0.f};
    __syncthreads();

    // scatter: 64 rows x 32 pairs = 2048 pairs, 8 per thread, coalesced reads
    const size_t tbase = (size_t)row0 * K_TOP;
    #pragma unroll
    for (int p = 0; p < 8; ++p) {
        int q = t + p * 256;             // 0..2047
        int r = q >> 5;                  // 0..63
        if (row0 + r < N_NODES) {
            int   ci = topk_i[tbase + q];
            float cv = topk_v[tbase + q];
            atomicAdd(&sx[r * D_IN + ci], cv);   // ds_add_f32, no return
        }
    }
    __syncthreads();

    // pack x -> bf16, coalesced: 4096 dwords, 16 per thread
    #pragma unroll
    for (int p = 0; p < 16; ++p) {
        int d = t + p * 256;             // dword index 0..4095
        int r = d >> 6;                  // 0..63
        int c2 = (d & 63) * 2;
        if (row0 + r < N_NODES) {
            float2 v = *(const float2*)&sx[r * D_IN + c2];
            ((unsigned*)(xbf + (size_t)(row0 + r) * D_IN))[d & 63] =
                pack_bf16_rne(v.x) | (pack_bf16_rne(v.y) << 16);
        }
    }

    // feat -> bf16 into A left half: 2048 float4, 8 per thread
    #pragma unroll
    for (int p = 0; p < 8; ++p) {
        int q = t + p * 256;             // 0..2047
        int r = q >> 5;                  // 0..63
        int c4 = (q & 31) * 4;
        if (row0 + r < N_NODES) {
            float4 f = *(const float4*)(feat + (size_t)(row0 + r) * D_IN + c4);
            uint2 pk;
            pk.x = pack_bf16_rne(f.x) | (pack_bf16_rne(f.y) << 16);
            pk.y = pack_bf16_rne(f.z) | (pack_bf16_rne(f.w) << 16);
            ((uint2*)(abf + (size_t)(row0 + r) * K_CAT))[q & 31] = pk;
        }
    }
}

// --------- kernel 3: SpMM — 4 rows per wave (quarter-wave per row), dwordx4 gathers ----
// Each quarter-wave (16 lanes) owns one destination row: lane ql holds edge ql's
// (col,w); 16 gather instrs per wave now cover 4 rows (was 2), 16B/lane.
__global__ __launch_bounds__(256) void k_spmm(const float* __restrict__ csr_w,
                                              const int* __restrict__ col_idx,
                                              const unsigned short* __restrict__ xbf,
                                              unsigned short* __restrict__ abf) {
    const int lane = threadIdx.x & 63;
    const int wave = threadIdx.x >> 6;
    const int ql   = lane & 15;              // edge id / channel group
    const int row  = blockIdx.x * 16 + wave * 4 + (lane >> 4);   // N%16==0 -> no guard
    const int qb   = lane & 48;              // quarter base for shuffles

    int   c = col_idx[row * DEG + ql];
    float w = csr_w[row * DEG + ql];

    uint4 vv[DEG];
    #pragma unroll
    for (int e = 0; e < DEG; ++e) {
        int col = __shfl(c, qb | e);
        vv[e] = *(const uint4*)(xbf + (size_t)col * D_IN + ql * 8);
    }
    float a[8] = {0.f, 0.f, 0.f, 0.f, 0.f, 0.f, 0.f, 0.f};
    #pragma unroll
    for (int e = 0; e < DEG; ++e) {
        float we = __shfl(w, qb | e);
        uint4 v = vv[e];
        a[0] += we * bf16lo_to_f(v.x & 0xffffu);
        a[1] += we * bf16lo_to_f(v.x >> 16);
        a[2] += we * bf16lo_to_f(v.y & 0xffffu);
        a[3] += we * bf16lo_to_f(v.y >> 16);
        a[4] += we * bf16lo_to_f(v.z & 0xffffu);
        a[5] += we * bf16lo_to_f(v.z >> 16);
        a[6] += we * bf16lo_to_f(v.w & 0xffffu);
        a[7] += we * bf16lo_to_f(v.w >> 16);
    }
    uint4 pk;
    pk.x = pack_bf16_rne(a[0]) | (pack_bf16_rne(a[1]) << 16);
    pk.y = pack_bf16_rne(a[2]) | (pack_bf16_rne(a[3]) << 16);
    pk.z = pack_bf16_rne(a[4]) | (pack_bf16_rne(a[5]) << 16);
    pk.w = pack_bf16_rne(a[6]) | (pack_bf16_rne(a[7]) << 16);
    *(uint4*)(abf + (size_t)row * K_CAT + D_IN + ql * 8) = pk;
}

// ------------- kernel 4: GEMM  out[N][256] = A[N][256] @ B[256][256]^T + bias ----------
// m97-style: BM=128, BN=128, BK=32; global_load_lds staging into double-buffered
// linear LDS, 1-deep prefetch, one barrier per K-step. 4 waves (2x2), each wave
// 64x64 = 4x4 mfma_f32_16x16x32_bf16 frags (64 acc regs). Operand-swapped MFMA so
// each lane holds 4 consecutive output columns -> float4 epilogue stores.
#define BM 128
#define BN 128
#define BK 32
#define NT (K_CAT / BK)   // 8

__global__ __launch_bounds__(256, 4) void k_gemm(const unsigned short* __restrict__ abf,
                                                 const unsigned short* __restrict__ bmat,
                                                 const float* __restrict__ bias,
                                                 float* __restrict__ out) {
    __shared__ __align__(16) unsigned short As[2][BM * BK];   // 2 x 8 KiB
    __shared__ __align__(16) unsigned short Bs[2][BN * BK];   // 2 x 8 KiB
    const int lane = threadIdx.x & 63, wave = threadIdx.x >> 6;
    const int wr = wave >> 1, wc = wave & 1;
    const int l16 = lane & 15, quad = lane >> 4;
    const int rt = blockIdx.x >> 1, ct = blockIdx.x & 1;   // paired col-tiles adjacent -> A panel L3-reuse
    const int row0 = rt * BM, n0 = ct * BN;

    // staging: each wave stages 32 rows of A and of B per K-step (2 x 1KiB instrs each).
    // lane l covers row (base + l>>2), 16B chunk (l&3); LDS dest = uniform base + lane*16.
    const int sr = wave * 32 + (lane >> 2);
    const int sc = (lane & 3) * 8;                          // shorts
    int arow0 = row0 + sr;      if (arow0 >= N_NODES) arow0 = N_NODES - 1;  // clamp: garbage
    int arow1 = row0 + sr + 16; if (arow1 >= N_NODES) arow1 = N_NODES - 1;  // rows never stored
    const int brow0 = n0 + sr, brow1 = n0 + sr + 16;
    const unsigned short* ga0 = abf  + (size_t)arow0 * K_CAT + sc;
    const unsigned short* ga1 = abf  + (size_t)arow1 * K_CAT + sc;
    const unsigned short* gb0 = bmat + (size_t)brow0 * K_CAT + sc;
    const unsigned short* gb1 = bmat + (size_t)brow1 * K_CAT + sc;

#define STAGE(buf, kt) do {                                                  \
        gload_lds16(ga0 + (kt), &As[buf][(wave * 32)      * BK]);            \
        gload_lds16(ga1 + (kt), &As[buf][(wave * 32 + 16) * BK]);            \
        gload_lds16(gb0 + (kt), &Bs[buf][(wave * 32)      * BK]);            \
        gload_lds16(gb1 + (kt), &Bs[buf][(wave * 32 + 16) * BK]);            \
    } while (0)

    floatx4 acc[4][4];
    #pragma unroll
    for (int i = 0; i < 4; ++i)
        #pragma unroll
        for (int j = 0; j < 4; ++j)
            acc[i][j] = (floatx4){0.f, 0.f, 0.f, 0.f};

    STAGE(0, 0);
    __syncthreads();            // compiler emits vmcnt(0) drain before s_barrier

    for (int t8 = 0; t8 < NT; ++t8) {
        const int cur = t8 & 1;
        if (t8 + 1 < NT) STAGE(cur ^ 1, (t8 + 1) * BK);   // prefetch hides under compute

        short8 afr[4], bfr[4];
        #pragma unroll
        for (int i = 0; i < 4; ++i)
            afr[i] = *(const short8*)&As[cur][(wr * 64 + i * 16 + l16) * BK + quad * 8];
        #pragma unroll
        for (int j = 0; j < 4; ++j)
            bfr[j] = *(const short8*)&Bs[cur][(wc * 64 + j * 16 + l16) * BK + quad * 8];

        #pragma unroll
        for (int i = 0; i < 4; ++i)
            #pragma unroll
            for (int j = 0; j < 4; ++j)   // swapped operands: D row-dim <- bfr (cols), col-dim <- afr (rows)
                acc[i][j] = __builtin_amdgcn_mfma_f32_16x16x32_bf16(bfr[j], afr[i], acc[i][j], 0, 0, 0);

        if (t8 + 1 < NT) __syncthreads();
    }

    // epilogue: lane holds output row m = l16 (+16i+64wr), cols quad*4..quad*4+3 (+16j+64wc)
    #pragma unroll
    for (int j = 0; j < 4; ++j) {
        const int cg = n0 + wc * 64 + j * 16 + quad * 4;
        const float4 bv = *(const float4*)&bias[cg];
        #pragma unroll
        for (int i = 0; i < 4; ++i) {
            const int gr = row0 + wr * 64 + i * 16 + l16;
            if (gr < N_NODES) {
                float4 v;
                v.x = acc[i][j][0] + bv.x;
                v.y = acc[i][j][1] + bv.y;
                v.z = acc[i][j][2] + bv.z;
                v.w = acc[i][j][3] + bv.w;
                *(float4*)(out + (size_t)gr * D_OUT + cg) = v;
            }
        }
    }
#undef STAGE
}

extern "C" void kernel_launch(void* const* d_in, const int* in_sizes, int n_in,
                              void* d_out, int out_size, void* d_ws, size_t ws_size,
                              hipStream_t stream) {
    const float* feat    = (const float*)d_in[0];
    const float* topk_v  = (const float*)d_in[1];
    const float* csr_w   = (const float*)d_in[2];
    const float* w_neigh = (const float*)d_in[3];
    const float* w_self  = (const float*)d_in[4];
    const float* b_self  = (const float*)d_in[5];
    const int*   topk_i  = (const int*)d_in[6];
    // d_in[7] = indptr (fixed degree 16, unused), d_in[8] = indices
    const int*   indices = (const int*)d_in[8];
    float* out = (float*)d_out;

    // workspace layout (bf16): x[N*128] | A[N*256] | B[256*256]  (~77 MB)
    unsigned short* xbf  = (unsigned short*)d_ws;
    unsigned short* abf  = xbf + (size_t)N_NODES * D_IN;
    unsigned short* bmat = abf + (size_t)N_NODES * K_CAT;

    k_packw<<<dim3(256), dim3(256), 0, stream>>>(w_self, w_neigh, bmat);
    k_densify<<<dim3((N_NODES + DROWS - 1) / DROWS), dim3(256), 0, stream>>>(topk_v, topk_i, feat, xbf, abf);
    k_spmm<<<dim3(N_NODES / 16), dim3(256), 0, stream>>>(csr_w, indices, xbf, abf);
    k_gemm<<<dim3(2 * ((N_NODES + BM - 1) / BM)), dim3(256), 0, stream>>>(abf, bmat, b_self, out);
}

// Round 2
// 296.191 us; speedup vs baseline: 1.0267x; 1.0215x over previous
//
#include <hip/hip_runtime.h>
#include <hip/hip_bf16.h>
#include <stdint.h>

#define N_NODES 100000
#define DEG 16
#define D_IN 128
#define D_OUT 256
#define K_TOP 32
#define K_CAT 256   // concatenated K = D_IN(self) + D_IN(neigh)

typedef __attribute__((ext_vector_type(8))) short short8;
typedef __attribute__((ext_vector_type(4))) float floatx4;

__device__ __forceinline__ unsigned pack_bf16_rne(float f) {
    union { float f; unsigned u; } c; c.f = f;
    unsigned u = c.u;
    return (u + 0x7fffu + ((u >> 16) & 1u)) >> 16;   // round-to-nearest-even
}
__device__ __forceinline__ float bf16lo_to_f(unsigned lo16) {
    union { unsigned u; float f; } c; c.u = lo16 << 16; return c.f;
}

// async global->LDS, 16B per lane; LDS dest is wave-uniform base + lane*16
typedef __attribute__((address_space(1))) void as1_void;
typedef __attribute__((address_space(3))) void as3_void;
__device__ __forceinline__ void gload_lds16(const void* g, void* l) {
    __builtin_amdgcn_global_load_lds((as1_void*)g, (as3_void*)l, 16, 0, 0);
}

// ---------------- kernel 1: pack [w_self | w_neigh] -> bf16 B[256][256] ----------------
__global__ __launch_bounds__(256) void k_packw(const float* __restrict__ w_self,
                                               const float* __restrict__ w_neigh,
                                               unsigned short* __restrict__ bmat) {
    int o = blockIdx.x;      // 0..255 output channel
    int k = threadIdx.x;     // 0..255 concat-K
    float v = (k < D_IN) ? w_self[o * D_IN + k] : w_neigh[o * D_IN + (k - D_IN)];
    bmat[o * K_CAT + k] = (unsigned short)pack_bf16_rne(v);
}

// ------------- kernel 2: densify via LDS ds_add_f32 scatter + feat->bf16 ---------------
// Writes xbf[N][128] (dense top-k features) and fbf[N][128] (feat as bf16, stride 128).
#define DROWS 64
__global__ __launch_bounds__(256) void k_densify(const float* __restrict__ topk_v,
                                                 const int* __restrict__ topk_i,
                                                 const float* __restrict__ feat,
                                                 unsigned short* __restrict__ xbf,
                                                 unsigned short* __restrict__ fbf) {
    __shared__ float sx[DROWS * D_IN];   // 32 KiB
    const int t = threadIdx.x;
    const int row0 = blockIdx.x * DROWS;

    // zero LDS: 8192 floats / 256 thr = 8 float4 per thread
    #pragma unroll
    for (int p = 0; p < 8; ++p)
        *(floatx4*)&sx[(t + p * 256) * 4] = (floatx4){0.f, 0.f, 0.f, 0.f};
    __syncthreads();

    // scatter: 64 rows x 32 pairs = 2048 pairs, 8 per thread, coalesced reads
    const size_t tbase = (size_t)row0 * K_TOP;
    #pragma unroll
    for (int p = 0; p < 8; ++p) {
        int q = t + p * 256;             // 0..2047
        int r = q >> 5;                  // 0..63
        if (row0 + r < N_NODES) {
            int   ci = topk_i[tbase + q];
            float cv = topk_v[tbase + q];
            atomicAdd(&sx[r * D_IN + ci], cv);   // ds_add_f32, no return
        }
    }
    __syncthreads();

    // pack x -> bf16, coalesced: 4096 dwords, 16 per thread
    #pragma unroll
    for (int p = 0; p < 16; ++p) {
        int d = t + p * 256;             // dword index 0..4095
        int r = d >> 6;                  // 0..63
        int c2 = (d & 63) * 2;
        if (row0 + r < N_NODES) {
            float2 v = *(const float2*)&sx[r * D_IN + c2];
            ((unsigned*)(xbf + (size_t)(row0 + r) * D_IN))[d & 63] =
                pack_bf16_rne(v.x) | (pack_bf16_rne(v.y) << 16);
        }
    }

    // feat -> bf16 into fbf (stride 128): 2048 float4, 8 per thread
    #pragma unroll
    for (int p = 0; p < 8; ++p) {
        int q = t + p * 256;             // 0..2047
        int r = q >> 5;                  // 0..63
        int c4 = (q & 31) * 4;
        if (row0 + r < N_NODES) {
            float4 f = *(const float4*)(feat + (size_t)(row0 + r) * D_IN + c4);
            uint2 pk;
            pk.x = pack_bf16_rne(f.x) | (pack_bf16_rne(f.y) << 16);
            pk.y = pack_bf16_rne(f.z) | (pack_bf16_rne(f.w) << 16);
            ((uint2*)(fbf + (size_t)(row0 + r) * D_IN))[q & 31] = pk;
        }
    }
}

// ------ kernel 3 (fused): per-block SpMM gather -> LDS agg, then GEMM over K=256 -------
// out[N][256] = [fbf | agg] @ B[256][256]^T + bias.
// BM=128 rows, BN=256 (full D_OUT, A read once), BK=32, 512 thr = 8 waves (2x4),
// each wave 64x64 out = 4x4 mfma_f32_16x16x32_bf16, swapped operands (cols in regs).
// K-steps 0..3: A = fbf via global_load_lds (double-buffered, 1-deep prefetch).
// K-steps 4..7: A = Agg read directly from LDS (XOR-swizzled vs 16-way bank conflict).
#define BM 128
#define BN 256
#define BK 32
#define NTA 4   // K-steps covered by fbf
#define NT  8

__global__ __launch_bounds__(512, 2) void k_fused(const float* __restrict__ csr_w,
                                                  const int* __restrict__ col_idx,
                                                  const unsigned short* __restrict__ xbf,
                                                  const unsigned short* __restrict__ fbf,
                                                  const unsigned short* __restrict__ bmat,
                                                  const float* __restrict__ bias,
                                                  float* __restrict__ out) {
    __shared__ __align__(16) unsigned short Agg[BM * 128];     // 32 KiB, swizzled
    __shared__ __align__(16) unsigned short As[2][BM * BK];    // 16 KiB
    __shared__ __align__(16) unsigned short Bs[2][BN * BK];    // 32 KiB
    const int t    = threadIdx.x;
    const int lane = t & 63, wave = t >> 6;
    const int l16  = lane & 15, quad = lane >> 4;
    const int row0 = blockIdx.x * BM;

    // staging geometry: each wave's 64 lanes cover 16 rows x 4x16B chunks (linear LDS)
    const int a_r = wave * 16 + (lane >> 2);
    const int a_c = (lane & 3) * 8;                          // shorts
    int a_gr = row0 + a_r; if (a_gr >= N_NODES) a_gr = N_NODES - 1;  // clamp: garbage
    const unsigned short* gA  = fbf  + (size_t)a_gr * D_IN + a_c;    // rows never stored
    const unsigned short* gB0 = bmat + (size_t)a_r        * K_CAT + a_c;
    const unsigned short* gB1 = bmat + (size_t)(a_r + 128) * K_CAT + a_c;

#define STAGE_A(buf, tt) gload_lds16(gA + (tt) * BK, &As[buf][wave * 16 * BK])
#define STAGE_B(buf, tt) do {                                                 \
        gload_lds16(gB0 + (tt) * BK, &Bs[buf][(wave * 16)       * BK]);       \
        gload_lds16(gB1 + (tt) * BK, &Bs[buf][(wave * 16 + 128) * BK]);       \
    } while (0)

    // issue first K-step staging now; it flies during the gather phase
    STAGE_A(0, 0);
    STAGE_B(0, 0);

    // ---- phase 1: aggregate 128 rows into Agg (quarter-wave per row, 4 passes) ----
    const int ql = lane & 15, qb = lane & 48;
    #pragma unroll 1
    for (int p = 0; p < 4; ++p) {
        const int r  = p * 32 + wave * 4 + (lane >> 4);      // 0..127
        const int gr = row0 + r;
        int   c = 0; float w = 0.f;
        if (gr < N_NODES) {
            c = col_idx[gr * DEG + ql];
            w = csr_w [gr * DEG + ql];
        }
        uint4 vv[DEG];
        #pragma unroll
        for (int e = 0; e < DEG; ++e) {
            int col = __shfl(c, qb | e);
            vv[e] = *(const uint4*)(xbf + (size_t)col * D_IN + ql * 8);
        }
        float a[8] = {0.f, 0.f, 0.f, 0.f, 0.f, 0.f, 0.f, 0.f};
        #pragma unroll
        for (int e = 0; e < DEG; ++e) {
            float we = __shfl(w, qb | e);
            uint4 v = vv[e];
            a[0] += we * bf16lo_to_f(v.x & 0xffffu);
            a[1] += we * bf16lo_to_f(v.x >> 16);
            a[2] += we * bf16lo_to_f(v.y & 0xffffu);
            a[3] += we * bf16lo_to_f(v.y >> 16);
            a[4] += we * bf16lo_to_f(v.z & 0xffffu);
            a[5] += we * bf16lo_to_f(v.z >> 16);
            a[6] += we * bf16lo_to_f(v.w & 0xffffu);
            a[7] += we * bf16lo_to_f(v.w >> 16);
        }
        uint4 pk;
        pk.x = pack_bf16_rne(a[0]) | (pack_bf16_rne(a[1]) << 16);
        pk.y = pack_bf16_rne(a[2]) | (pack_bf16_rne(a[3]) << 16);
        pk.z = pack_bf16_rne(a[4]) | (pack_bf16_rne(a[5]) << 16);
        pk.w = pack_bf16_rne(a[6]) | (pack_bf16_rne(a[7]) << 16);
        // swizzled write: shorts [r][ (ql*8) ^ ((r&7)<<3) ]
        *(uint4*)&Agg[r * 128 + ((ql * 8) ^ ((r & 7) << 3))] = pk;
    }

    // ---- phase 2: GEMM K-loop ----
    const int wr = wave >> 2, wc = wave & 3;                 // 2x4 wave grid, 64x64 each
    floatx4 acc[4][4];
    #pragma unroll
    for (int i = 0; i < 4; ++i)
        #pragma unroll
        for (int j = 0; j < 4; ++j)
            acc[i][j] = (floatx4){0.f, 0.f, 0.f, 0.f};

    __syncthreads();   // drains vmcnt(0): buf0 staged + Agg writes visible

    #pragma unroll
    for (int tt = 0; tt < NT; ++tt) {
        const int cur = tt & 1;
        if (tt + 1 < NTA) STAGE_A(cur ^ 1, tt + 1);          // prefetch next A (fbf half)
        if (tt + 1 < NT)  STAGE_B(cur ^ 1, tt + 1);          // prefetch next B

        short8 afr[4], bfr[4];
        if (tt < NTA) {
            #pragma unroll
            for (int i = 0; i < 4; ++i)
                afr[i] = *(const short8*)&As[cur][(wr * 64 + i * 16 + l16) * BK + quad * 8];
        } else {
            const int c0 = (tt - NTA) * 32 + quad * 8;
            #pragma unroll
            for (int i = 0; i < 4; ++i) {
                const int m = wr * 64 + i * 16 + l16;
                afr[i] = *(const short8*)&Agg[m * 128 + (c0 ^ ((m & 7) << 3))];
            }
        }
        #pragma unroll
        for (int j = 0; j < 4; ++j)
            bfr[j] = *(const short8*)&Bs[cur][(wc * 64 + j * 16 + l16) * BK + quad * 8];

        #pragma unroll
        for (int i = 0; i < 4; ++i)
            #pragma unroll
            for (int j = 0; j < 4; ++j)   // swapped: out-rows <- afr lanes, out-cols <- bfr regs
                acc[i][j] = __builtin_amdgcn_mfma_f32_16x16x32_bf16(bfr[j], afr[i], acc[i][j], 0, 0, 0);

        if (tt + 1 < NT) __syncthreads();
    }

    // epilogue: lane holds row m = l16 (+16i+64wr), cols quad*4..+3 (+16j+64wc) -> float4
    #pragma unroll
    for (int j = 0; j < 4; ++j) {
        const int cg = wc * 64 + j * 16 + quad * 4;
        const float4 bv = *(const float4*)&bias[cg];
        #pragma unroll
        for (int i = 0; i < 4; ++i) {
            const int gr = row0 + wr * 64 + i * 16 + l16;
            if (gr < N_NODES) {
                float4 v;
                v.x = acc[i][j][0] + bv.x;
                v.y = acc[i][j][1] + bv.y;
                v.z = acc[i][j][2] + bv.z;
                v.w = acc[i][j][3] + bv.w;
                *(float4*)(out + (size_t)gr * D_OUT + cg) = v;
            }
        }
    }
#undef STAGE_A
#undef STAGE_B
}

extern "C" void kernel_launch(void* const* d_in, const int* in_sizes, int n_in,
                              void* d_out, int out_size, void* d_ws, size_t ws_size,
                              hipStream_t stream) {
    const float* feat    = (const float*)d_in[0];
    const float* topk_v  = (const float*)d_in[1];
    const float* csr_w   = (const float*)d_in[2];
    const float* w_neigh = (const float*)d_in[3];
    const float* w_self  = (const float*)d_in[4];
    const float* b_self  = (const float*)d_in[5];
    const int*   topk_i  = (const int*)d_in[6];
    // d_in[7] = indptr (fixed degree 16, unused), d_in[8] = indices
    const int*   indices = (const int*)d_in[8];
    float* out = (float*)d_out;

    // workspace layout (bf16): x[N*128] | f[N*128] | B[256*256]  (~51.4 MB)
    unsigned short* xbf  = (unsigned short*)d_ws;
    unsigned short* fbf  = xbf + (size_t)N_NODES * D_IN;
    unsigned short* bmat = fbf + (size_t)N_NODES * D_IN;

    k_packw<<<dim3(256), dim3(256), 0, stream>>>(w_self, w_neigh, bmat);
    k_densify<<<dim3((N_NODES + DROWS - 1) / DROWS), dim3(256), 0, stream>>>(topk_v, topk_i, feat, xbf, fbf);
    k_fused<<<dim3((N_NODES + BM - 1) / BM), dim3(512), 0, stream>>>(csr_w, indices, xbf, fbf, bmat, b_self, out);
}